// Round 1
// baseline (1304.067 us; speedup 1.0000x reference)
//
#include <hip/hip_runtime.h>
#include <cstddef>

#define B_   2
#define C_   1024
#define N_   4096   // H*W
#define M_   8192   // B*N
#define K2_  2048   // 2C
#define E_   4
#define HE_  512

static __device__ __forceinline__ unsigned short f2bf(float f) {
  unsigned int u = __float_as_uint(f);
  u = u + 0x7fffu + ((u >> 16) & 1u);
  return (unsigned short)(u >> 16);
}
static __device__ __forceinline__ float bf2f(unsigned short h) {
  return __uint_as_float(((unsigned int)h) << 16);
}

// ---------------- kernel 1: s = mean over HW of (x+t), per (b,c) ----------------
__global__ __launch_bounds__(256) void k_reduce_s(const float* __restrict__ x,
                                                  const float* __restrict__ t,
                                                  float* __restrict__ s) {
  const int bc = blockIdx.x;                 // 0..B*C-1
  const float* xp = x + (size_t)bc * N_;
  const float* tp = t + (size_t)bc * N_;
  float acc = 0.f;
  for (int i = threadIdx.x; i < N_ / 4; i += 256) {
    const float4 a = ((const float4*)xp)[i];
    const float4 b = ((const float4*)tp)[i];
    acc += ((a.x + b.x) + (a.y + b.y)) + ((a.z + b.z) + (a.w + b.w));
  }
  #pragma unroll
  for (int o = 32; o; o >>= 1) acc += __shfl_down(acc, o);
  __shared__ float red[4];
  if ((threadIdx.x & 63) == 0) red[threadIdx.x >> 6] = acc;
  __syncthreads();
  if (threadIdx.x == 0)
    s[bc] = (red[0] + red[1] + red[2] + red[3]) * (1.f / (float)N_);
}

// ---------------- kernel 2: SE dual-branch gate -> wts0 [B,C] ----------------
__global__ __launch_bounds__(256) void k_se_gate(const float* __restrict__ s,
                                                 const float* __restrict__ w1, const float* __restrict__ b1,
                                                 const float* __restrict__ wa, const float* __restrict__ ba,
                                                 const float* __restrict__ wb, const float* __restrict__ bbv,
                                                 float* __restrict__ wts0) {
  __shared__ float hid[2][64];
  const int t = threadIdx.x;
  if (t < 128) {
    const int b = t >> 6, r = t & 63;
    float acc = b1[r];
    const float* sp = s + b * C_;
    const float* wp = w1 + r * C_;
    for (int c = 0; c < C_; ++c) acc = fmaf(sp[c], wp[c], acc);
    hid[b][r] = fmaxf(acc, 0.f);
  }
  __syncthreads();
  for (int o = t; o < B_ * C_; o += 256) {
    const int b = o >> 10, c = o & 1023;
    float a = ba[c], bb = bbv[c];
    #pragma unroll 8
    for (int r = 0; r < 64; ++r) {
      const float h = hid[b][r];
      a  = fmaf(h, wa[c * 64 + r], a);
      bb = fmaf(h, wb[c * 64 + r], bb);
    }
    wts0[o] = 1.f / (1.f + expf(bb - a));   // softmax over {a,bb} -> weight of x
  }
}

// inner product micro-kernel shared by the three GEMMs
#define MMA_INNER(AS, BS)                                                       \
  do {                                                                          \
    _Pragma("unroll")                                                           \
    for (int kk = 0; kk < 16; ++kk) {                                           \
      const float4 a0 = *(const float4*)&AS[kk][ty * 8];                        \
      const float4 a1 = *(const float4*)&AS[kk][ty * 8 + 4];                    \
      const float4 b0 = *(const float4*)&BS[kk][tx * 8];                        \
      const float4 b1 = *(const float4*)&BS[kk][tx * 8 + 4];                    \
      const float am[8] = {a0.x, a0.y, a0.z, a0.w, a1.x, a1.y, a1.z, a1.w};     \
      const float bn[8] = {b0.x, b0.y, b0.z, b0.w, b1.x, b1.y, b1.z, b1.w};     \
      _Pragma("unroll")                                                         \
      for (int i = 0; i < 8; ++i) {                                             \
        _Pragma("unroll")                                                       \
        for (int j = 0; j < 8; ++j) acc[i][j] = fmaf(am[i], bn[j], acc[i][j]);  \
      }                                                                         \
    }                                                                           \
  } while (0)

// ---------------- kernel 3: y = relu([x3|t3] @ fc_w^T), f32, tile 128x128x16 ----------------
__global__ __launch_bounds__(256) void k_fc_gemm(const float* __restrict__ x,
                                                 const float* __restrict__ tt,
                                                 const float* __restrict__ fcw,
                                                 float* __restrict__ y) {
  __shared__ __align__(16) float As[16][128];
  __shared__ __align__(16) float Bs[16][128];
  const int tid = threadIdx.x;
  const int m0 = blockIdx.y * 128;
  const int n0 = blockIdx.x * 128;
  const int tx = tid & 15, ty = tid >> 4;
  float acc[8][8] = {};
  const int bb = m0 >> 12;          // batch index (tiles never straddle batches)
  const int nn = m0 & 4095;         // pixel base
  const float* xb = x  + (size_t)bb * C_ * N_ + nn;
  const float* tb = tt + (size_t)bb * C_ * N_ + nn;
  for (int k0 = 0; k0 < K2_; k0 += 16) {
    #pragma unroll
    for (int p = 0; p < 2; ++p) {      // A tile: [16 k][128 m], coalesced along m
      const int f = tid + p * 256;
      const int kk = f >> 5, mq = f & 31;
      const int k = k0 + kk;
      const float* src = (k < C_) ? (xb + (size_t)k * N_) : (tb + (size_t)(k - C_) * N_);
      *(float4*)&As[kk][mq * 4] = *(const float4*)(src + mq * 4);
    }
    #pragma unroll
    for (int p = 0; p < 2; ++p) {      // B tile: fc_w[n0+co, k0..k0+15], transpose into LDS
      const int f = tid + p * 256;
      const int co = f >> 2, kq = f & 3;
      const float4 v = *(const float4*)(fcw + (size_t)(n0 + co) * K2_ + k0 + kq * 4);
      Bs[kq * 4 + 0][co] = v.x; Bs[kq * 4 + 1][co] = v.y;
      Bs[kq * 4 + 2][co] = v.z; Bs[kq * 4 + 3][co] = v.w;
    }
    __syncthreads();
    MMA_INNER(As, Bs);
    __syncthreads();
  }
  #pragma unroll
  for (int i = 0; i < 8; ++i) {        // relu + store
    const int m = m0 + ty * 8 + i;
    float* dst = y + (size_t)m * C_ + n0 + tx * 8;
    float4 v0, v1;
    v0.x = fmaxf(acc[i][0], 0.f); v0.y = fmaxf(acc[i][1], 0.f);
    v0.z = fmaxf(acc[i][2], 0.f); v0.w = fmaxf(acc[i][3], 0.f);
    v1.x = fmaxf(acc[i][4], 0.f); v1.y = fmaxf(acc[i][5], 0.f);
    v1.z = fmaxf(acc[i][6], 0.f); v1.w = fmaxf(acc[i][7], 0.f);
    *(float4*)dst = v0; *(float4*)(dst + 4) = v1;
  }
}

// ---------------- kernel 4: LayerNorm + logits + top-2 gates (one wave per token) ----------------
__global__ __launch_bounds__(256) void k_ln_topk(const float* __restrict__ y,
                                                 const float* __restrict__ lng, const float* __restrict__ lnb,
                                                 const float* __restrict__ wg, const int* __restrict__ taskp,
                                                 unsigned short* __restrict__ yf, float* __restrict__ gates) {
  const int wv = threadIdx.x >> 6, ln = threadIdx.x & 63;
  const int m = blockIdx.x * 4 + wv;
  const float* yr = y + (size_t)m * C_;
  float4 v[4];
  #pragma unroll
  for (int ch = 0; ch < 4; ++ch) v[ch] = *(const float4*)(yr + ch * 256 + ln * 4);
  float sum = 0.f;
  #pragma unroll
  for (int ch = 0; ch < 4; ++ch) sum += (v[ch].x + v[ch].y) + (v[ch].z + v[ch].w);
  #pragma unroll
  for (int o = 32; o; o >>= 1) sum += __shfl_down(sum, o);
  sum = __shfl(sum, 0);
  const float mu = sum * (1.f / 1024.f);
  float q = 0.f;
  #pragma unroll
  for (int ch = 0; ch < 4; ++ch) {
    const float dx = v[ch].x - mu, dy = v[ch].y - mu, dz = v[ch].z - mu, dw = v[ch].w - mu;
    q += (dx * dx + dy * dy) + (dz * dz + dw * dw);
  }
  #pragma unroll
  for (int o = 32; o; o >>= 1) q += __shfl_down(q, o);
  q = __shfl(q, 0);
  const float rstd = rsqrtf(q * (1.f / 1024.f) + 1e-5f);
  const float* wrow = wg + (size_t)(*taskp) * (C_ * E_);
  float l0 = 0.f, l1 = 0.f, l2 = 0.f, l3 = 0.f;
  #pragma unroll
  for (int ch = 0; ch < 4; ++ch) {
    const int c = ch * 256 + ln * 4;
    const float4 gg = *(const float4*)(lng + c);
    const float4 bv = *(const float4*)(lnb + c);
    float f[4];
    f[0] = (v[ch].x - mu) * rstd * gg.x + bv.x;
    f[1] = (v[ch].y - mu) * rstd * gg.y + bv.y;
    f[2] = (v[ch].z - mu) * rstd * gg.z + bv.z;
    f[3] = (v[ch].w - mu) * rstd * gg.w + bv.w;
    uint2 pk;
    pk.x = (unsigned)f2bf(f[0]) | ((unsigned)f2bf(f[1]) << 16);
    pk.y = (unsigned)f2bf(f[2]) | ((unsigned)f2bf(f[3]) << 16);
    *(uint2*)(yf + (size_t)m * C_ + c) = pk;
    #pragma unroll
    for (int i = 0; i < 4; ++i) {     // logits in f32 from pre-rounding values
      const float4 we = *(const float4*)(wrow + (size_t)(c + i) * 4);
      l0 = fmaf(f[i], we.x, l0); l1 = fmaf(f[i], we.y, l1);
      l2 = fmaf(f[i], we.z, l2); l3 = fmaf(f[i], we.w, l3);
    }
  }
  #pragma unroll
  for (int o = 32; o; o >>= 1) {
    l0 += __shfl_down(l0, o); l1 += __shfl_down(l1, o);
    l2 += __shfl_down(l2, o); l3 += __shfl_down(l3, o);
  }
  if (ln == 0) {
    const float L[4] = {l0, l1, l2, l3};
    int i1 = 0; float best = L[0];
    #pragma unroll
    for (int e = 1; e < 4; ++e) if (L[e] > best) { best = L[e]; i1 = e; }
    int i2 = -1; float s2 = 0.f;
    #pragma unroll
    for (int e = 0; e < 4; ++e) if (e != i1 && (i2 < 0 || L[e] > s2)) { s2 = L[e]; i2 = e; }
    const float g1 = 1.f / (1.f + expf(s2 - best));
    const float g2 = 1.f - g1;
    float4 gv;
    gv.x = (i1 == 0) ? g1 : ((i2 == 0) ? g2 : 0.f);
    gv.y = (i1 == 1) ? g1 : ((i2 == 1) ? g2 : 0.f);
    gv.z = (i1 == 2) ? g1 : ((i2 == 2) ? g2 : 0.f);
    gv.w = (i1 == 3) ? g1 : ((i2 == 3) ? g2 : 0.f);
    *(float4*)(gates + (size_t)m * 4) = gv;
  }
}

// ---------------- kernel 5: EHG = gate * relu(yf @ e_w1 + b1), bf16 out ----------------
__global__ __launch_bounds__(256) void k_moe1(const unsigned short* __restrict__ yf,
                                              const float* __restrict__ w1, const float* __restrict__ b1,
                                              const float* __restrict__ gates,
                                              unsigned short* __restrict__ ehg) {
  __shared__ __align__(16) float As[16][128];
  __shared__ __align__(16) float Bs[16][128];
  const int tid = threadIdx.x;
  const int m0 = blockIdx.y * 128;
  const int j0 = blockIdx.x * 128;     // expert-block column: e0 = j0>>9
  const int e0 = j0 >> 9;
  const int h0 = j0 & 511;
  const int tx = tid & 15, ty = tid >> 4;
  float acc[8][8] = {};
  for (int k0 = 0; k0 < C_; k0 += 16) {
    {   // A: yf bf16 row-major -> transpose+convert into LDS
      const int mm = tid >> 1, kq = tid & 1;
      const uint4 raw = *(const uint4*)(yf + (size_t)(m0 + mm) * C_ + k0 + kq * 8);
      As[kq * 8 + 0][mm] = bf2f((unsigned short)(raw.x & 0xffff));
      As[kq * 8 + 1][mm] = bf2f((unsigned short)(raw.x >> 16));
      As[kq * 8 + 2][mm] = bf2f((unsigned short)(raw.y & 0xffff));
      As[kq * 8 + 3][mm] = bf2f((unsigned short)(raw.y >> 16));
      As[kq * 8 + 4][mm] = bf2f((unsigned short)(raw.z & 0xffff));
      As[kq * 8 + 5][mm] = bf2f((unsigned short)(raw.z >> 16));
      As[kq * 8 + 6][mm] = bf2f((unsigned short)(raw.w & 0xffff));
      As[kq * 8 + 7][mm] = bf2f((unsigned short)(raw.w >> 16));
    }
    #pragma unroll
    for (int p = 0; p < 2; ++p) {      // B: e_w1[e0, k, h0+nn], coalesced along h
      const int f = tid + p * 256;
      const int kk = f >> 5, nq = f & 31;
      *(float4*)&Bs[kk][nq * 4] =
        *(const float4*)(w1 + (size_t)e0 * C_ * HE_ + (size_t)(k0 + kk) * HE_ + h0 + nq * 4);
    }
    __syncthreads();
    MMA_INNER(As, Bs);
    __syncthreads();
  }
  const float4 bi0 = *(const float4*)(b1 + e0 * HE_ + h0 + tx * 8);
  const float4 bi1 = *(const float4*)(b1 + e0 * HE_ + h0 + tx * 8 + 4);
  const float bia[8] = {bi0.x, bi0.y, bi0.z, bi0.w, bi1.x, bi1.y, bi1.z, bi1.w};
  #pragma unroll
  for (int i = 0; i < 8; ++i) {
    const int m = m0 + ty * 8 + i;
    const float gt = gates[(size_t)m * 4 + e0];
    float vv[8];
    #pragma unroll
    for (int j = 0; j < 8; ++j) vv[j] = fmaxf(acc[i][j] + bia[j], 0.f) * gt;
    uint4 pk;
    pk.x = (unsigned)f2bf(vv[0]) | ((unsigned)f2bf(vv[1]) << 16);
    pk.y = (unsigned)f2bf(vv[2]) | ((unsigned)f2bf(vv[3]) << 16);
    pk.z = (unsigned)f2bf(vv[4]) | ((unsigned)f2bf(vv[5]) << 16);
    pk.w = (unsigned)f2bf(vv[6]) | ((unsigned)f2bf(vv[7]) << 16);
    *(uint4*)(ehg + (size_t)m * K2_ + j0 + tx * 8) = pk;
  }
}

// ---------------- kernel 6: ym = EHG @ W2flat + sum_e g*b2, f32 out (reuses y buffer) ----------------
__global__ __launch_bounds__(256) void k_moe2(const unsigned short* __restrict__ ehg,
                                              const float* __restrict__ w2, const float* __restrict__ b2,
                                              const float* __restrict__ gates,
                                              float* __restrict__ ym) {
  __shared__ __align__(16) float As[16][128];
  __shared__ __align__(16) float Bs[16][128];
  const int tid = threadIdx.x;
  const int m0 = blockIdx.y * 128;
  const int n0 = blockIdx.x * 128;
  const int tx = tid & 15, ty = tid >> 4;
  float acc[8][8] = {};
  for (int k0 = 0; k0 < K2_; k0 += 16) {
    {
      const int mm = tid >> 1, kq = tid & 1;
      const uint4 raw = *(const uint4*)(ehg + (size_t)(m0 + mm) * K2_ + k0 + kq * 8);
      As[kq * 8 + 0][mm] = bf2f((unsigned short)(raw.x & 0xffff));
      As[kq * 8 + 1][mm] = bf2f((unsigned short)(raw.x >> 16));
      As[kq * 8 + 2][mm] = bf2f((unsigned short)(raw.y & 0xffff));
      As[kq * 8 + 3][mm] = bf2f((unsigned short)(raw.y >> 16));
      As[kq * 8 + 4][mm] = bf2f((unsigned short)(raw.z & 0xffff));
      As[kq * 8 + 5][mm] = bf2f((unsigned short)(raw.z >> 16));
      As[kq * 8 + 6][mm] = bf2f((unsigned short)(raw.w & 0xffff));
      As[kq * 8 + 7][mm] = bf2f((unsigned short)(raw.w >> 16));
    }
    #pragma unroll
    for (int p = 0; p < 2; ++p) {
      const int f = tid + p * 256;
      const int kk = f >> 5, nq = f & 31;
      *(float4*)&Bs[kk][nq * 4] = *(const float4*)(w2 + (size_t)(k0 + kk) * C_ + n0 + nq * 4);
    }
    __syncthreads();
    MMA_INNER(As, Bs);
    __syncthreads();
  }
  float b2v[4][8];
  #pragma unroll
  for (int e = 0; e < 4; ++e) {
    const float4 u0 = *(const float4*)(b2 + e * C_ + n0 + tx * 8);
    const float4 u1 = *(const float4*)(b2 + e * C_ + n0 + tx * 8 + 4);
    b2v[e][0] = u0.x; b2v[e][1] = u0.y; b2v[e][2] = u0.z; b2v[e][3] = u0.w;
    b2v[e][4] = u1.x; b2v[e][5] = u1.y; b2v[e][6] = u1.z; b2v[e][7] = u1.w;
  }
  #pragma unroll
  for (int i = 0; i < 8; ++i) {
    const int m = m0 + ty * 8 + i;
    const float4 g = *(const float4*)(gates + (size_t)m * 4);
    float out8[8];
    #pragma unroll
    for (int j = 0; j < 8; ++j)
      out8[j] = acc[i][j] + g.x * b2v[0][j] + g.y * b2v[1][j] + g.z * b2v[2][j] + g.w * b2v[3][j];
    float* dst = ym + (size_t)m * C_ + n0 + tx * 8;
    float4 v0 = {out8[0], out8[1], out8[2], out8[3]};
    float4 v1 = {out8[4], out8[5], out8[6], out8[7]};
    *(float4*)dst = v0; *(float4*)(dst + 4) = v1;
  }
}

// ---------------- kernel 7: aux loss (deterministic single-block reduction) ----------------
__global__ __launch_bounds__(256) void k_aux(const float* __restrict__ gates, float* __restrict__ outp) {
  const int t = threadIdx.x;
  float imp[4] = {0, 0, 0, 0}, ld[4] = {0, 0, 0, 0};
  for (int m = t; m < M_; m += 256) {
    const float4 g = *(const float4*)(gates + (size_t)m * 4);
    imp[0] += g.x; imp[1] += g.y; imp[2] += g.z; imp[3] += g.w;
    ld[0] += (g.x > 0.f) ? 1.f : 0.f; ld[1] += (g.y > 0.f) ? 1.f : 0.f;
    ld[2] += (g.z > 0.f) ? 1.f : 0.f; ld[3] += (g.w > 0.f) ? 1.f : 0.f;
  }
  __shared__ float red[8][4];
  const int wv = t >> 6, ln = t & 63;
  #pragma unroll
  for (int e = 0; e < 4; ++e) {
    float a = imp[e], b = ld[e];
    #pragma unroll
    for (int o = 32; o; o >>= 1) { a += __shfl_down(a, o); b += __shfl_down(b, o); }
    if (ln == 0) { red[e][wv] = a; red[4 + e][wv] = b; }
  }
  __syncthreads();
  if (t == 0) {
    float I[4], L[4];
    #pragma unroll
    for (int e = 0; e < 4; ++e) {
      I[e] = red[e][0] + red[e][1] + red[e][2] + red[e][3];
      L[e] = red[4 + e][0] + red[4 + e][1] + red[4 + e][2] + red[4 + e][3];
    }
    const float mi = (I[0] + I[1] + I[2] + I[3]) * 0.25f;
    const float vi = ((I[0] - mi) * (I[0] - mi) + (I[1] - mi) * (I[1] - mi) +
                      (I[2] - mi) * (I[2] - mi) + (I[3] - mi) * (I[3] - mi)) / 3.f;
    const float ml = (L[0] + L[1] + L[2] + L[3]) * 0.25f;
    const float vl = ((L[0] - ml) * (L[0] - ml) + (L[1] - ml) * (L[1] - ml) +
                      (L[2] - ml) * (L[2] - ml) + (L[3] - ml) * (L[3] - ml)) / 3.f;
    *outp = vi / (mi * mi + 1e-10f) + vl / (ml * ml + 1e-10f);
  }
}

// ---------------- kernel 8: transpose ym [m,c]->[b,c,n], add z = w0*x+(1-w0)*t ----------------
__global__ __launch_bounds__(256) void k_final(const float* __restrict__ ym,
                                               const float* __restrict__ x, const float* __restrict__ t,
                                               const float* __restrict__ wts0, float* __restrict__ out) {
  __shared__ float tile[64][65];
  const int c0 = blockIdx.x * 64, n0 = blockIdx.y * 64, b = blockIdx.z;
  const int tid = threadIdx.x;
  #pragma unroll
  for (int p = 0; p < 4; ++p) {
    const int f = tid + p * 256;
    const int row = f >> 4, cq = f & 15;       // row = local n, cq*4 = local c
    const float4 v = *(const float4*)(ym + (size_t)(b * N_ + n0 + row) * C_ + c0 + cq * 4);
    tile[row][cq * 4 + 0] = v.x; tile[row][cq * 4 + 1] = v.y;
    tile[row][cq * 4 + 2] = v.z; tile[row][cq * 4 + 3] = v.w;
  }
  __syncthreads();
  #pragma unroll
  for (int p = 0; p < 4; ++p) {
    const int f = tid + p * 256;
    const int cr = f >> 4, nq = f & 15;        // cr = local c, nq*4 = local n
    const int c = c0 + cr;
    const float w0 = wts0[b * C_ + c];
    const float w1 = 1.f - w0;
    const size_t idx = (size_t)(b * C_ + c) * N_ + n0 + nq * 4;
    const float4 xv = *(const float4*)(x + idx);
    const float4 tv = *(const float4*)(t + idx);
    float4 o;
    o.x = tile[nq * 4 + 0][cr] + w0 * xv.x + w1 * tv.x;
    o.y = tile[nq * 4 + 1][cr] + w0 * xv.y + w1 * tv.y;
    o.z = tile[nq * 4 + 2][cr] + w0 * xv.z + w1 * tv.z;
    o.w = tile[nq * 4 + 3][cr] + w0 * xv.w + w1 * tv.w;
    *(float4*)(out + idx) = o;
  }
}

extern "C" void kernel_launch(void* const* d_in, const int* in_sizes, int n_in,
                              void* d_out, int out_size, void* d_ws, size_t ws_size,
                              hipStream_t stream) {
  const float* x     = (const float*)d_in[0];
  const float* t     = (const float*)d_in[1];
  const float* fc_w  = (const float*)d_in[2];
  const float* ln_g  = (const float*)d_in[3];
  const float* ln_b  = (const float*)d_in[4];
  const float* f1_w1 = (const float*)d_in[5];
  const float* f1_b1 = (const float*)d_in[6];
  const float* f1_wa = (const float*)d_in[7];
  const float* f1_ba = (const float*)d_in[8];
  const float* f1_wb = (const float*)d_in[9];
  const float* f1_bb = (const float*)d_in[10];
  const float* w_gate = (const float*)d_in[11];
  const float* e_w1  = (const float*)d_in[12];
  const float* e_b1  = (const float*)d_in[13];
  const float* e_w2  = (const float*)d_in[14];
  const float* e_b2  = (const float*)d_in[15];
  const int*   task  = (const int*)d_in[16];
  float* out = (float*)d_out;

  char* ws = (char*)d_ws;
  float*          y     = (float*)ws;                        // 33.5 MB (reused as ym)
  unsigned short* yf    = (unsigned short*)(ws + 33554432);  // 16.8 MB bf16
  unsigned short* ehg   = (unsigned short*)(ws + 50331648);  // 33.5 MB bf16
  float*          sbuf  = (float*)(ws + 83886080);           // 8 KB
  float*          wts0  = (float*)(ws + 83894272);           // 8 KB
  float*          gates = (float*)(ws + 83902464);           // 128 KB

  k_reduce_s<<<B_ * C_, 256, 0, stream>>>(x, t, sbuf);
  k_se_gate<<<1, 256, 0, stream>>>(sbuf, f1_w1, f1_b1, f1_wa, f1_ba, f1_wb, f1_bb, wts0);
  k_fc_gemm<<<dim3(C_ / 128, M_ / 128), 256, 0, stream>>>(x, t, fc_w, y);
  k_ln_topk<<<M_ / 4, 256, 0, stream>>>(y, ln_g, ln_b, w_gate, task, yf, gates);
  k_moe1<<<dim3(K2_ / 128, M_ / 128), 256, 0, stream>>>(yf, e_w1, e_b1, gates, ehg);
  k_moe2<<<dim3(C_ / 128, M_ / 128), 256, 0, stream>>>(ehg, e_w2, e_b2, gates, y);
  k_aux<<<1, 256, 0, stream>>>(gates, out + (size_t)B_ * C_ * N_);
  k_final<<<dim3(C_ / 64, N_ / 64, B_), 256, 0, stream>>>(y, x, t, wts0, out);
}

// Round 2
// 434.210 us; speedup vs baseline: 3.0033x; 3.0033x over previous
//
#include <hip/hip_runtime.h>
#include <cstddef>
#include <cstdint>

#define B_   2
#define C_   1024
#define N_   4096   // H*W
#define M_   8192   // B*N
#define K2_  2048   // 2C
#define E_   4
#define HE_  512

typedef float f32x4 __attribute__((ext_vector_type(4)));
typedef short bf16x8 __attribute__((ext_vector_type(8)));
typedef _Float16 f16x8 __attribute__((ext_vector_type(8)));
typedef unsigned short u16x8 __attribute__((ext_vector_type(8)));

static __device__ __forceinline__ unsigned short f2bf(float f) {
  unsigned int u = __float_as_uint(f);
  u = u + 0x7fffu + ((u >> 16) & 1u);
  return (unsigned short)(u >> 16);
}

// global -> LDS direct copy, 16B per lane. LDS dest must be wave-uniform;
// HW writes at dest + lane*16. Global src is per-lane. (CK addrspace pattern.)
static __device__ __forceinline__ void gl_lds16(const void* g, void* l) {
  __builtin_amdgcn_global_load_lds(
      (const __attribute__((address_space(1))) void*)(uintptr_t)g,
      (__attribute__((address_space(3))) void*)(unsigned)(uintptr_t)l,
      16, 0, 0);
}

// pack 8 f32 -> 8 bf16 (RNE) via v_cvt_pk_bf16_f32
static __device__ __forceinline__ bf16x8 cvt8(f32x4 a, f32x4 b) {
  union { unsigned u[4]; bf16x8 s; } r;
  asm("v_cvt_pk_bf16_f32 %0, %1, %2" : "=v"(r.u[0]) : "v"(a[0]), "v"(a[1]));
  asm("v_cvt_pk_bf16_f32 %0, %1, %2" : "=v"(r.u[1]) : "v"(a[2]), "v"(a[3]));
  asm("v_cvt_pk_bf16_f32 %0, %1, %2" : "=v"(r.u[2]) : "v"(b[0]), "v"(b[1]));
  asm("v_cvt_pk_bf16_f32 %0, %1, %2" : "=v"(r.u[3]) : "v"(b[2]), "v"(b[3]));
  return r.s;
}

// ---------------- kernel 1: s = mean over HW of (x+t), per (b,c) ----------------
__global__ __launch_bounds__(256) void k_reduce_s(const float* __restrict__ x,
                                                  const float* __restrict__ t,
                                                  float* __restrict__ s) {
  const int bc = blockIdx.x;
  const float* xp = x + (size_t)bc * N_;
  const float* tp = t + (size_t)bc * N_;
  float acc = 0.f;
  for (int i = threadIdx.x; i < N_ / 4; i += 256) {
    const float4 a = ((const float4*)xp)[i];
    const float4 b = ((const float4*)tp)[i];
    acc += ((a.x + b.x) + (a.y + b.y)) + ((a.z + b.z) + (a.w + b.w));
  }
  #pragma unroll
  for (int o = 32; o; o >>= 1) acc += __shfl_down(acc, o);
  __shared__ float red[4];
  if ((threadIdx.x & 63) == 0) red[threadIdx.x >> 6] = acc;
  __syncthreads();
  if (threadIdx.x == 0)
    s[bc] = (red[0] + red[1] + red[2] + red[3]) * (1.f / (float)N_);
}

// ---------------- kernel 2: SE dual-branch gate -> wts0 [B,C] ----------------
__global__ __launch_bounds__(256) void k_se_gate(const float* __restrict__ s,
                                                 const float* __restrict__ w1, const float* __restrict__ b1,
                                                 const float* __restrict__ wa, const float* __restrict__ ba,
                                                 const float* __restrict__ wb, const float* __restrict__ bbv,
                                                 float* __restrict__ wts0) {
  __shared__ float hid[2][64];
  const int t = threadIdx.x;
  if (t < 128) {
    const int b = t >> 6, r = t & 63;
    float acc = b1[r];
    const float* sp = s + b * C_;
    const float* wp = w1 + r * C_;
    for (int c = 0; c < C_; ++c) acc = fmaf(sp[c], wp[c], acc);
    hid[b][r] = fmaxf(acc, 0.f);
  }
  __syncthreads();
  for (int o = t; o < B_ * C_; o += 256) {
    const int b = o >> 10, c = o & 1023;
    float a = ba[c], bb = bbv[c];
    #pragma unroll 8
    for (int r = 0; r < 64; ++r) {
      const float h = hid[b][r];
      a  = fmaf(h, wa[c * 64 + r], a);
      bb = fmaf(h, wb[c * 64 + r], bb);
    }
    wts0[o] = 1.f / (1.f + expf(bb - a));
  }
}

// ---------------- prep: x,t [C][N] f32 -> a_hi,a_mid fp16 [4096 m][2048 k], scale 64 ----------------
__global__ __launch_bounds__(256) void k_prep_act(const float* __restrict__ xb,
                                                  const float* __restrict__ tb,
                                                  _Float16* __restrict__ ah,
                                                  _Float16* __restrict__ am) {
  __shared__ float tile[64][65];
  const int c0 = blockIdx.x * 64, n0 = blockIdx.y * 64;
  const int tid = threadIdx.x;
  #pragma unroll
  for (int srcsel = 0; srcsel < 2; ++srcsel) {
    const float* src = srcsel ? tb : xb;
    const int koff = srcsel ? C_ : 0;
    if (srcsel) __syncthreads();
    #pragma unroll
    for (int p = 0; p < 4; ++p) {
      const int f = tid + p * 256;
      const int cr = f >> 4, nq = f & 15;
      const float4 v = *(const float4*)(src + (size_t)(c0 + cr) * N_ + n0 + nq * 4);
      tile[cr][nq * 4 + 0] = v.x; tile[cr][nq * 4 + 1] = v.y;
      tile[cr][nq * 4 + 2] = v.z; tile[cr][nq * 4 + 3] = v.w;
    }
    __syncthreads();
    #pragma unroll
    for (int p = 0; p < 2; ++p) {
      const int f = tid + p * 256;
      const int mr = f >> 3, kq = f & 7;
      f16x8 hv, mv;
      #pragma unroll
      for (int u = 0; u < 8; ++u) {
        const float v = tile[kq * 8 + u][mr] * 64.f;
        const _Float16 h = (_Float16)v;
        hv[u] = h;
        mv[u] = (_Float16)(v - (float)h);
      }
      const size_t off = (size_t)(n0 + mr) * K2_ + koff + c0 + kq * 8;
      *(f16x8*)(ah + off) = hv;
      *(f16x8*)(am + off) = mv;
    }
  }
}

// ---------------- prep: fc_w [1024][2048] f32 -> w_hi,w_mid fp16, scale 4096 ----------------
__global__ __launch_bounds__(256) void k_prep_fcw(const float* __restrict__ w,
                                                  _Float16* __restrict__ wh,
                                                  _Float16* __restrict__ wm) {
  const size_t i = ((size_t)blockIdx.x * 256 + threadIdx.x) * 8;
  const float4 v0 = *(const float4*)(w + i);
  const float4 v1 = *(const float4*)(w + i + 4);
  const float vv[8] = {v0.x, v0.y, v0.z, v0.w, v1.x, v1.y, v1.z, v1.w};
  f16x8 hv, mv;
  #pragma unroll
  for (int u = 0; u < 8; ++u) {
    const float sv = vv[u] * 4096.f;
    const _Float16 h = (_Float16)sv;
    hv[u] = h;
    mv[u] = (_Float16)(sv - (float)h);
  }
  *(f16x8*)(wh + i) = hv;
  *(f16x8*)(wm + i) = mv;
}

// ---------------- prep: generic f32 [R][Cc] -> bf16 transposed [Cc][R] per z-slice ----------------
__global__ __launch_bounds__(256) void k_prep_tr(const float* __restrict__ src, long long zs, int srs,
                                                 unsigned short* __restrict__ dst, long long zo, int drs) {
  __shared__ float tile[64][65];
  const int c0 = blockIdx.x * 64, r0 = blockIdx.y * 64, z = blockIdx.z;
  const float* s = src + (size_t)z * zs;
  unsigned short* d = dst + (size_t)z * zo;
  const int tid = threadIdx.x;
  #pragma unroll
  for (int p = 0; p < 4; ++p) {
    const int f = tid + p * 256;
    const int rr = f >> 4, cq = f & 15;
    const float4 v = *(const float4*)(s + (size_t)(r0 + rr) * srs + c0 + cq * 4);
    tile[rr][cq * 4 + 0] = v.x; tile[rr][cq * 4 + 1] = v.y;
    tile[rr][cq * 4 + 2] = v.z; tile[rr][cq * 4 + 3] = v.w;
  }
  __syncthreads();
  #pragma unroll
  for (int p = 0; p < 2; ++p) {
    const int f = tid + p * 256;
    const int cr = f >> 3, rq = f & 7;
    u16x8 o;
    #pragma unroll
    for (int u = 0; u < 8; ++u) o[u] = f2bf(tile[rq * 8 + u][cr]);
    *(u16x8*)(d + (size_t)(c0 + cr) * drs + r0 + rq * 8) = o;
  }
}

// ---------------- fc GEMM: y = relu((A_hi+A_mid)@(W_hi+W_mid)^T * 2^-18), fp16 split-MFMA ----------------
// A*: [Mrows][2048] fp16, W*: [1024][2048] fp16, tile 128x128x32, 4 waves
__global__ __launch_bounds__(256) void k_fc_mfma(const _Float16* __restrict__ Ah,
                                                 const _Float16* __restrict__ Am,
                                                 const _Float16* __restrict__ Bh,
                                                 const _Float16* __restrict__ Bm,
                                                 float* __restrict__ y) {
  __shared__ __align__(16) _Float16 lAh[4096], lAm[4096], lBh[4096], lBm[4096]; // 8KB each
  const int tid = threadIdx.x, w = tid >> 6, l = tid & 63;
  const int m0 = blockIdx.y * 128, n0 = blockIdx.x * 128;
  const int wr = w >> 1, wc = w & 1, lg = l >> 4, lr = l & 15;
  f32x4 acc[4][4] = {};
  for (int k0 = 0; k0 < K2_; k0 += 32) {
    #pragma unroll
    for (int p = 0; p < 2; ++p) {
      const int c = w * 2 + p;
      const int i = c * 64 + l;
      const int g = i >> 7, row = i & 127;
      const size_t ga = (size_t)(m0 + row) * K2_ + k0 + g * 8;
      const size_t gb = (size_t)(n0 + row) * K2_ + k0 + g * 8;
      gl_lds16(Ah + ga, (char*)lAh + c * 1024);
      gl_lds16(Am + ga, (char*)lAm + c * 1024);
      gl_lds16(Bh + gb, (char*)lBh + c * 1024);
      gl_lds16(Bm + gb, (char*)lBm + c * 1024);
    }
    __syncthreads();
    f16x8 ah[4], am[4], bh[4], bm[4];
    #pragma unroll
    for (int i = 0; i < 4; ++i) {
      const int off = (lg * 128 + wr * 64 + i * 16 + lr) * 8;
      ah[i] = *(const f16x8*)&lAh[off];
      am[i] = *(const f16x8*)&lAm[off];
    }
    #pragma unroll
    for (int j = 0; j < 4; ++j) {
      const int off = (lg * 128 + wc * 64 + j * 16 + lr) * 8;
      bh[j] = *(const f16x8*)&lBh[off];
      bm[j] = *(const f16x8*)&lBm[off];
    }
    #pragma unroll
    for (int i = 0; i < 4; ++i)
      #pragma unroll
      for (int j = 0; j < 4; ++j) {
        acc[i][j] = __builtin_amdgcn_mfma_f32_16x16x32_f16(ah[i], bh[j], acc[i][j], 0, 0, 0);
        acc[i][j] = __builtin_amdgcn_mfma_f32_16x16x32_f16(ah[i], bm[j], acc[i][j], 0, 0, 0);
        acc[i][j] = __builtin_amdgcn_mfma_f32_16x16x32_f16(am[i], bh[j], acc[i][j], 0, 0, 0);
      }
    __syncthreads();
  }
  #pragma unroll
  for (int i = 0; i < 4; ++i) {
    const int mb = m0 + wr * 64 + i * 16 + lg * 4;
    #pragma unroll
    for (int j = 0; j < 4; ++j) {
      const int n = n0 + wc * 64 + j * 16 + lr;
      #pragma unroll
      for (int r = 0; r < 4; ++r)
        y[(size_t)(mb + r) * C_ + n] = fmaxf(acc[i][j][r] * (1.f / 262144.f), 0.f);
    }
  }
}

// ---------------- LayerNorm (in place) + logits + top-2 gates, one wave per token ----------------
__global__ __launch_bounds__(256) void k_ln_topk(float* __restrict__ y,
                                                 const float* __restrict__ lng, const float* __restrict__ lnb,
                                                 const float* __restrict__ wg, const int* __restrict__ taskp,
                                                 float* __restrict__ gates) {
  const int wv = threadIdx.x >> 6, ln = threadIdx.x & 63;
  const int m = blockIdx.x * 4 + wv;
  float* yr = y + (size_t)m * C_;
  float4 v[4];
  #pragma unroll
  for (int ch = 0; ch < 4; ++ch) v[ch] = *(const float4*)(yr + ch * 256 + ln * 4);
  float sum = 0.f;
  #pragma unroll
  for (int ch = 0; ch < 4; ++ch) sum += (v[ch].x + v[ch].y) + (v[ch].z + v[ch].w);
  #pragma unroll
  for (int o = 32; o; o >>= 1) sum += __shfl_down(sum, o);
  sum = __shfl(sum, 0);
  const float mu = sum * (1.f / 1024.f);
  float q = 0.f;
  #pragma unroll
  for (int ch = 0; ch < 4; ++ch) {
    const float dx = v[ch].x - mu, dy = v[ch].y - mu, dz = v[ch].z - mu, dw = v[ch].w - mu;
    q += (dx * dx + dy * dy) + (dz * dz + dw * dw);
  }
  #pragma unroll
  for (int o = 32; o; o >>= 1) q += __shfl_down(q, o);
  q = __shfl(q, 0);
  const float rstd = rsqrtf(q * (1.f / 1024.f) + 1e-5f);
  const float* wrow = wg + (size_t)(*taskp) * (C_ * E_);
  float l0 = 0.f, l1 = 0.f, l2 = 0.f, l3 = 0.f;
  #pragma unroll
  for (int ch = 0; ch < 4; ++ch) {
    const int c = ch * 256 + ln * 4;
    const float4 gg = *(const float4*)(lng + c);
    const float4 bv = *(const float4*)(lnb + c);
    float f[4];
    f[0] = (v[ch].x - mu) * rstd * gg.x + bv.x;
    f[1] = (v[ch].y - mu) * rstd * gg.y + bv.y;
    f[2] = (v[ch].z - mu) * rstd * gg.z + bv.z;
    f[3] = (v[ch].w - mu) * rstd * gg.w + bv.w;
    float4 wb; wb.x = f[0]; wb.y = f[1]; wb.z = f[2]; wb.w = f[3];
    *(float4*)(yr + c) = wb;                       // post-LN, in place
    #pragma unroll
    for (int i = 0; i < 4; ++i) {
      const float4 we = *(const float4*)(wrow + (size_t)(c + i) * 4);
      l0 = fmaf(f[i], we.x, l0); l1 = fmaf(f[i], we.y, l1);
      l2 = fmaf(f[i], we.z, l2); l3 = fmaf(f[i], we.w, l3);
    }
  }
  #pragma unroll
  for (int o = 32; o; o >>= 1) {
    l0 += __shfl_down(l0, o); l1 += __shfl_down(l1, o);
    l2 += __shfl_down(l2, o); l3 += __shfl_down(l3, o);
  }
  if (ln == 0) {
    const float L[4] = {l0, l1, l2, l3};
    int i1 = 0; float best = L[0];
    #pragma unroll
    for (int e = 1; e < 4; ++e) if (L[e] > best) { best = L[e]; i1 = e; }
    int i2 = -1; float s2 = 0.f;
    #pragma unroll
    for (int e = 0; e < 4; ++e) if (e != i1 && (i2 < 0 || L[e] > s2)) { s2 = L[e]; i2 = e; }
    const float g1 = 1.f / (1.f + expf(s2 - best));
    const float g2 = 1.f - g1;
    float4 gv;
    gv.x = (i1 == 0) ? g1 : ((i2 == 0) ? g2 : 0.f);
    gv.y = (i1 == 1) ? g1 : ((i2 == 1) ? g2 : 0.f);
    gv.z = (i1 == 2) ? g1 : ((i2 == 2) ? g2 : 0.f);
    gv.w = (i1 == 3) ? g1 : ((i2 == 3) ? g2 : 0.f);
    *(float4*)(gates + (size_t)m * 4) = gv;
  }
}

// ---------------- moe1: ehg = gate * relu(Y_postLN @ w1t^T + b1), bf16 MFMA, f32 A converted in-frag ----------------
__global__ __launch_bounds__(256) void k_moe1_mfma(const float* __restrict__ Y,
                                                   const short* __restrict__ Bw,
                                                   const float* __restrict__ b1,
                                                   const float* __restrict__ gates,
                                                   unsigned short* __restrict__ ehg) {
  __shared__ __align__(16) float lA[4096];   // [4 g][128 row][8 k] f32, 16KB
  __shared__ __align__(16) short lB[4096];   // [4 g][128 col][8 k] bf16, 8KB
  const int tid = threadIdx.x, w = tid >> 6, l = tid & 63;
  const int m0 = blockIdx.y * 128, n0 = blockIdx.x * 128;
  const int wr = w >> 1, wc = w & 1, lg = l >> 4, lr = l & 15;
  f32x4 acc[4][4] = {};
  for (int k0 = 0; k0 < C_; k0 += 32) {
    #pragma unroll
    for (int p = 0; p < 4; ++p) {
      const int c = w * 4 + p;
      const int q = c * 64 + l;
      const int g = q >> 8, row = (q >> 1) & 127, jh = q & 1;
      gl_lds16(Y + (size_t)(m0 + row) * C_ + k0 + g * 8 + jh * 4, (char*)lA + c * 1024);
    }
    #pragma unroll
    for (int p = 0; p < 2; ++p) {
      const int c = w * 2 + p;
      const int i = c * 64 + l;
      const int g = i >> 7, row = i & 127;
      gl_lds16(Bw + (size_t)(n0 + row) * C_ + k0 + g * 8, (char*)lB + c * 1024);
    }
    __syncthreads();
    bf16x8 af[4], bfr[4];
    #pragma unroll
    for (int i = 0; i < 4; ++i) {
      const int off = (lg * 128 + wr * 64 + i * 16 + lr) * 8;
      const f32x4 a0 = *(const f32x4*)&lA[off];
      const f32x4 a1 = *(const f32x4*)&lA[off + 4];
      af[i] = cvt8(a0, a1);
    }
    #pragma unroll
    for (int j = 0; j < 4; ++j)
      bfr[j] = *(const bf16x8*)&lB[(lg * 128 + wc * 64 + j * 16 + lr) * 8];
    #pragma unroll
    for (int i = 0; i < 4; ++i)
      #pragma unroll
      for (int j = 0; j < 4; ++j)
        acc[i][j] = __builtin_amdgcn_mfma_f32_16x16x32_bf16(af[i], bfr[j], acc[i][j], 0, 0, 0);
    __syncthreads();
  }
  const int e0 = n0 >> 9;
  #pragma unroll
  for (int j = 0; j < 4; ++j) {
    const int n = n0 + wc * 64 + j * 16 + lr;
    const float bias = b1[e0 * HE_ + (n & 511)];
    #pragma unroll
    for (int i = 0; i < 4; ++i) {
      const int mb = m0 + wr * 64 + i * 16 + lg * 4;
      #pragma unroll
      for (int r = 0; r < 4; ++r) {
        const float g = gates[(size_t)(mb + r) * 4 + e0];
        const float v = fmaxf(acc[i][j][r] + bias, 0.f) * g;
        ehg[(size_t)(mb + r) * K2_ + n] = f2bf(v);
      }
    }
  }
}

// ---------------- moe2: ym = ehg @ w2t^T + sum_e g*b2, bf16 MFMA ----------------
__global__ __launch_bounds__(256) void k_moe2_mfma(const short* __restrict__ Aeh,
                                                   const short* __restrict__ Bw,
                                                   const float* __restrict__ b2,
                                                   const float* __restrict__ gates,
                                                   float* __restrict__ ym) {
  __shared__ __align__(16) short lA[4096];   // 8KB
  __shared__ __align__(16) short lB[4096];   // 8KB
  const int tid = threadIdx.x, w = tid >> 6, l = tid & 63;
  const int m0 = blockIdx.y * 128, n0 = blockIdx.x * 128;
  const int wr = w >> 1, wc = w & 1, lg = l >> 4, lr = l & 15;
  f32x4 acc[4][4] = {};
  for (int k0 = 0; k0 < K2_; k0 += 32) {
    #pragma unroll
    for (int p = 0; p < 2; ++p) {
      const int c = w * 2 + p;
      const int i = c * 64 + l;
      const int g = i >> 7, row = i & 127;
      gl_lds16(Aeh + (size_t)(m0 + row) * K2_ + k0 + g * 8, (char*)lA + c * 1024);
      gl_lds16(Bw + (size_t)(n0 + row) * K2_ + k0 + g * 8, (char*)lB + c * 1024);
    }
    __syncthreads();
    bf16x8 af[4], bfr[4];
    #pragma unroll
    for (int i = 0; i < 4; ++i)
      af[i] = *(const bf16x8*)&lA[(lg * 128 + wr * 64 + i * 16 + lr) * 8];
    #pragma unroll
    for (int j = 0; j < 4; ++j)
      bfr[j] = *(const bf16x8*)&lB[(lg * 128 + wc * 64 + j * 16 + lr) * 8];
    #pragma unroll
    for (int i = 0; i < 4; ++i)
      #pragma unroll
      for (int j = 0; j < 4; ++j)
        acc[i][j] = __builtin_amdgcn_mfma_f32_16x16x32_bf16(af[i], bfr[j], acc[i][j], 0, 0, 0);
    __syncthreads();
  }
  float bb[4][4];  // [j][e]
  #pragma unroll
  for (int j = 0; j < 4; ++j) {
    const int n = n0 + wc * 64 + j * 16 + lr;
    #pragma unroll
    for (int e = 0; e < 4; ++e) bb[j][e] = b2[e * C_ + n];
  }
  #pragma unroll
  for (int i = 0; i < 4; ++i) {
    const int mb = m0 + wr * 64 + i * 16 + lg * 4;
    #pragma unroll
    for (int r = 0; r < 4; ++r) {
      const float4 g = *(const float4*)(gates + (size_t)(mb + r) * 4);
      #pragma unroll
      for (int j = 0; j < 4; ++j) {
        const int n = n0 + wc * 64 + j * 16 + lr;
        ym[(size_t)(mb + r) * C_ + n] =
            acc[i][j][r] + g.x * bb[j][0] + g.y * bb[j][1] + g.z * bb[j][2] + g.w * bb[j][3];
      }
    }
  }
}

// ---------------- aux loss (deterministic single-block reduction) ----------------
__global__ __launch_bounds__(256) void k_aux(const float* __restrict__ gates, float* __restrict__ outp) {
  const int t = threadIdx.x;
  float imp[4] = {0, 0, 0, 0}, ld[4] = {0, 0, 0, 0};
  for (int m = t; m < M_; m += 256) {
    const float4 g = *(const float4*)(gates + (size_t)m * 4);
    imp[0] += g.x; imp[1] += g.y; imp[2] += g.z; imp[3] += g.w;
    ld[0] += (g.x > 0.f) ? 1.f : 0.f; ld[1] += (g.y > 0.f) ? 1.f : 0.f;
    ld[2] += (g.z > 0.f) ? 1.f : 0.f; ld[3] += (g.w > 0.f) ? 1.f : 0.f;
  }
  __shared__ float red[8][4];
  const int wv = t >> 6, ln = t & 63;
  #pragma unroll
  for (int e = 0; e < 4; ++e) {
    float a = imp[e], b = ld[e];
    #pragma unroll
    for (int o = 32; o; o >>= 1) { a += __shfl_down(a, o); b += __shfl_down(b, o); }
    if (ln == 0) { red[e][wv] = a; red[4 + e][wv] = b; }
  }
  __syncthreads();
  if (t == 0) {
    float I[4], L[4];
    #pragma unroll
    for (int e = 0; e < 4; ++e) {
      I[e] = red[e][0] + red[e][1] + red[e][2] + red[e][3];
      L[e] = red[4 + e][0] + red[4 + e][1] + red[4 + e][2] + red[4 + e][3];
    }
    const float mi = (I[0] + I[1] + I[2] + I[3]) * 0.25f;
    const float vi = ((I[0] - mi) * (I[0] - mi) + (I[1] - mi) * (I[1] - mi) +
                      (I[2] - mi) * (I[2] - mi) + (I[3] - mi) * (I[3] - mi)) / 3.f;
    const float ml = (L[0] + L[1] + L[2] + L[3]) * 0.25f;
    const float vl = ((L[0] - ml) * (L[0] - ml) + (L[1] - ml) * (L[1] - ml) +
                      (L[2] - ml) * (L[2] - ml) + (L[3] - ml) * (L[3] - ml)) / 3.f;
    *outp = vi / (mi * mi + 1e-10f) + vl / (ml * ml + 1e-10f);
  }
}

// ---------------- final: transpose ym [m,c]->[b,c,n], add z = w0*x+(1-w0)*t ----------------
__global__ __launch_bounds__(256) void k_final(const float* __restrict__ ym,
                                               const float* __restrict__ x, const float* __restrict__ t,
                                               const float* __restrict__ wts0, float* __restrict__ out) {
  __shared__ float tile[64][65];
  const int c0 = blockIdx.x * 64, n0 = blockIdx.y * 64, b = blockIdx.z;
  const int tid = threadIdx.x;
  #pragma unroll
  for (int p = 0; p < 4; ++p) {
    const int f = tid + p * 256;
    const int row = f >> 4, cq = f & 15;
    const float4 v = *(const float4*)(ym + (size_t)(b * N_ + n0 + row) * C_ + c0 + cq * 4);
    tile[row][cq * 4 + 0] = v.x; tile[row][cq * 4 + 1] = v.y;
    tile[row][cq * 4 + 2] = v.z; tile[row][cq * 4 + 3] = v.w;
  }
  __syncthreads();
  #pragma unroll
  for (int p = 0; p < 4; ++p) {
    const int f = tid + p * 256;
    const int cr = f >> 4, nq = f & 15;
    const int c = c0 + cr;
    const float w0 = wts0[b * C_ + c];
    const float w1 = 1.f - w0;
    const size_t idx = (size_t)(b * C_ + c) * N_ + n0 + nq * 4;
    const float4 xv = *(const float4*)(x + idx);
    const float4 tv = *(const float4*)(t + idx);
    float4 o;
    o.x = tile[nq * 4 + 0][cr] + w0 * xv.x + w1 * tv.x;
    o.y = tile[nq * 4 + 1][cr] + w0 * xv.y + w1 * tv.y;
    o.z = tile[nq * 4 + 2][cr] + w0 * xv.z + w1 * tv.z;
    o.w = tile[nq * 4 + 3][cr] + w0 * xv.w + w1 * tv.w;
    *(float4*)(out + idx) = o;
  }
}

extern "C" void kernel_launch(void* const* d_in, const int* in_sizes, int n_in,
                              void* d_out, int out_size, void* d_ws, size_t ws_size,
                              hipStream_t stream) {
  const float* x     = (const float*)d_in[0];
  const float* t     = (const float*)d_in[1];
  const float* fc_w  = (const float*)d_in[2];
  const float* ln_g  = (const float*)d_in[3];
  const float* ln_b  = (const float*)d_in[4];
  const float* f1_w1 = (const float*)d_in[5];
  const float* f1_b1 = (const float*)d_in[6];
  const float* f1_wa = (const float*)d_in[7];
  const float* f1_ba = (const float*)d_in[8];
  const float* f1_wb = (const float*)d_in[9];
  const float* f1_bb = (const float*)d_in[10];
  const float* w_gate = (const float*)d_in[11];
  const float* e_w1  = (const float*)d_in[12];
  const float* e_b1  = (const float*)d_in[13];
  const float* e_w2  = (const float*)d_in[14];
  const float* e_b2  = (const float*)d_in[15];
  const int*   task  = (const int*)d_in[16];
  float* out = (float*)d_out;

  char* ws = (char*)d_ws;
  const bool big = ws_size >= 117587968ull;
  float*          y    = (float*)ws;                                  // 33.55 MB (fc out -> postLN -> ym)
  unsigned short* ehg  = (unsigned short*)(ws + 33554432);            // 33.55 MB (aliases a-buffers, dead by then)
  _Float16 *ah, *am; char *W, *SM;
  if (big) {
    ah = (_Float16*)(ws + 33554432);   // full [8192][2048]
    am = (_Float16*)(ws + 67108864);
    W  = ws + 100663296;
    SM = ws + 117440512;
  } else {
    ah = (_Float16*)(ws + 33554432);   // half [4096][2048]
    am = (_Float16*)(ws + 50331648);
    W  = ws + 67108864;
    SM = ws + 83886080;
  }
  _Float16* wh  = (_Float16*)W;
  _Float16* wm  = (_Float16*)(W + 4194304);
  short*    w1t = (short*)(W + 8388608);
  short*    w2t = (short*)(W + 12582912);
  float* sbuf  = (float*)SM;
  float* wts0  = (float*)(SM + 8192);
  float* gates = (float*)(SM + 16384);

  k_reduce_s<<<B_ * C_, 256, 0, stream>>>(x, t, sbuf);
  k_se_gate<<<1, 256, 0, stream>>>(sbuf, f1_w1, f1_b1, f1_wa, f1_ba, f1_wb, f1_bb, wts0);
  k_prep_fcw<<<1024, 256, 0, stream>>>(fc_w, wh, wm);
  k_prep_tr<<<dim3(8, 16, 4), 256, 0, stream>>>(e_w1, 524288LL, 512, (unsigned short*)w1t, 524288LL, 1024);
  k_prep_tr<<<dim3(16, 8, 4), 256, 0, stream>>>(e_w2, 524288LL, 1024, (unsigned short*)w2t, 512LL, 2048);
  if (big) {
    k_prep_act<<<dim3(16, 64), 256, 0, stream>>>(x, t, ah, am);
    k_prep_act<<<dim3(16, 64), 256, 0, stream>>>(x + 4194304, t + 4194304, ah + 8388608, am + 8388608);
    k_fc_mfma<<<dim3(8, 64), 256, 0, stream>>>(ah, am, wh, wm, y);
  } else {
    for (int b = 0; b < 2; ++b) {
      k_prep_act<<<dim3(16, 64), 256, 0, stream>>>(x + (size_t)b * 4194304, t + (size_t)b * 4194304, ah, am);
      k_fc_mfma<<<dim3(8, 32), 256, 0, stream>>>(ah, am, wh, wm, y + (size_t)b * 4194304);
    }
  }
  k_ln_topk<<<M_ / 4, 256, 0, stream>>>(y, ln_g, ln_b, w_gate, task, gates);
  k_moe1_mfma<<<dim3(16, 64), 256, 0, stream>>>(y, w1t, e_b1, gates, ehg);
  k_moe2_mfma<<<dim3(8, 64), 256, 0, stream>>>((const short*)ehg, w2t, e_b2, gates, y);
  k_aux<<<1, 256, 0, stream>>>(gates, out + (size_t)B_ * C_ * N_);
  k_final<<<dim3(C_ / 64, N_ / 64, B_), 256, 0, stream>>>(y, x, t, wts0, out);
}